// Round 8
// baseline (154.962 us; speedup 1.0000x reference)
//
#include <hip/hip_runtime.h>

// SpatialEncoding: out[N,N]=0; out[src[e],dst[e]] = b[clip(path_len[e],1,5)-1],
// last edge wins for duplicate (src,dst). Resolution via max over
// key = ((e+1)<<3)|bias_idx  (order-independent -> deterministic).
//
// Fast path (N=8192), 2 kernels, intermediates live inside d_out:
//   rec(u64) = key[51:26] | src[25:13] | dst[12:0]; rec==0 is a no-op pad.
//   stage1: chunk-sort (8192 edges/WG, 1024 thr) into 1024 slabs (8 rows each).
//           Slab s's list is stored in its own 8 output rows (contiguous
//           32768 u64 slots; mean load ~11.3K incl pads). Per-chunk per-slab
//           allocations rounded to 8 recs (64B) and zero-padded -> line-aligned
//           runs, no partial-line RMW.
//   resolve: one WG per slab. Read the slab list once (nontemporal), sub-bin
//           into 8 per-row LDS lists (cap 1536, mean 977, 18 sigma), then per
//           row: zero 32KB LDS key table, atomicMax, decode, nontemporal row
//           write. No pair-list intermediate in HBM (saves ~128MB vs r7).

typedef float floatx4 __attribute__((ext_vector_type(4)));
typedef unsigned int uintx4 __attribute__((ext_vector_type(4)));

constexpr int MAXPD      = 5;
constexpr int NROW       = 8192;
constexpr int SLAB_ROWS  = 8;
constexpr int NSLAB      = NROW / SLAB_ROWS;       // 1024
constexpr int SLOTS_ROW  = NROW / 2;               // 4096 u64 per row
constexpr int SLAB_SLOTS = SLAB_ROWS * SLOTS_ROW;  // 32768 u64 per slab
constexpr int SUB_CAP    = 1536;                   // per-row list cap (mean 977, sd 31)
constexpr int CHUNK      = 8192;                   // edges per stage-1 WG
constexpr int CUR_PAD    = 16;                     // slab cursors 1 per 64B line
constexpr int E_MAX      = 8388606;                // (e+1)<<3 must fit 26 bits

__device__ __forceinline__ float dec(unsigned int k, float b0, float b1,
                                     float b2, float b3, float b4) {
    if (k == 0u) return 0.0f;
    unsigned int bi = k & 7u;
    float v = b0;
    v = (bi == 1u) ? b1 : v;
    v = (bi == 2u) ? b2 : v;
    v = (bi == 3u) ? b3 : v;
    v = (bi == 4u) ? b4 : v;
    return v;
}

__global__ void zero_ws_kernel(unsigned int* __restrict__ w, int n) {
    int i = blockIdx.x * blockDim.x + threadIdx.x;
    if (i < n) w[i] = 0u;
}

// ---------------- stage 1: chunk-sort edges into 1024 slab lists ----------------

__global__ __launch_bounds__(1024) void stage1_bin(
        const int* __restrict__ gsrc, const int* __restrict__ gdst,
        const int* __restrict__ gpl, unsigned long long* __restrict__ out64,
        unsigned int* __restrict__ slabcur, int E) {
    __shared__ unsigned long long sorted[CHUNK];   // 64 KB
    __shared__ unsigned int hist[NSLAB];           // 4 KB each
    __shared__ unsigned int offs[NSLAB];
    __shared__ unsigned int cur2[NSLAB];
    __shared__ unsigned int gbase[NSLAB];
    __shared__ unsigned int wsum[16];

    const int t = threadIdx.x;                     // blockDim == NSLAB == 1024
    const int base = blockIdx.x * CHUNK;
    const int cnt = min(CHUNK, E - base);

    hist[t] = 0u;
    __syncthreads();

    unsigned long long rec[8];

    #pragma unroll
    for (int k = 0; k < 2; ++k) {
        int g = base + (k * 1024 + t) * 4;
        bool full = (g + 3 < E);
        int4 s4 = {0,0,0,0}, d4 = {0,0,0,0}, p4 = {1,1,1,1};
        if (full) {
            s4 = ((const int4*)gsrc)[g >> 2];
            d4 = ((const int4*)gdst)[g >> 2];
            p4 = ((const int4*)gpl)[g >> 2];
        }
        #pragma unroll
        for (int j = 0; j < 4; ++j) {
            int e = g + j;
            unsigned long long r = 0ull;
            if (full || e < E) {
                int ss, dd, pp;
                if (full) {
                    ss = (j == 0) ? s4.x : (j == 1) ? s4.y : (j == 2) ? s4.z : s4.w;
                    dd = (j == 0) ? d4.x : (j == 1) ? d4.y : (j == 2) ? d4.z : d4.w;
                    pp = (j == 0) ? p4.x : (j == 1) ? p4.y : (j == 2) ? p4.z : p4.w;
                } else {
                    ss = gsrc[e]; dd = gdst[e]; pp = gpl[e];
                }
                int bi = pp < 1 ? 0 : (pp > MAXPD ? MAXPD - 1 : pp - 1);
                unsigned int key = (((unsigned int)e + 1u) << 3) | (unsigned int)bi;
                r = ((unsigned long long)key << 26) |
                    ((unsigned long long)(unsigned int)ss << 13) |
                    (unsigned long long)(unsigned int)dd;
                atomicAdd(&hist[(unsigned int)ss >> 3], 1u);   // slab = src>>3
            }
            rec[k * 4 + j] = r;
        }
    }
    __syncthreads();

    // exclusive scan of hist[1024]: wave64 scan + 16-entry cross-wave fixup
    unsigned int h = hist[t];
    unsigned int incl = h;
    #pragma unroll
    for (int d = 1; d < 64; d <<= 1) {
        unsigned int v = __shfl_up(incl, d, 64);
        if ((t & 63) >= d) incl += v;
    }
    if ((t & 63) == 63) wsum[t >> 6] = incl;
    __syncthreads();
    unsigned int wpre = 0;
    for (int w = 0; w < (t >> 6); ++w) wpre += wsum[w];
    unsigned int excl = wpre + incl - h;
    offs[t] = excl;
    cur2[t] = excl;
    unsigned int hpad = (h + 7u) & ~7u;            // 64B-aligned allocation
    gbase[t] = atomicAdd(&slabcur[t * CUR_PAD], hpad);
    __syncthreads();

    // reorder into LDS by slab
    #pragma unroll
    for (int m = 0; m < 8; ++m) {
        unsigned long long r = rec[m];
        if (r) {
            unsigned int slab = (unsigned int)(r >> 16) & 1023u;  // src>>3
            unsigned int p = atomicAdd(&cur2[slab], 1u);
            sorted[p] = r;
        }
    }
    __syncthreads();

    // write out: per-slab contiguous 64B-aligned runs (mean ~8 recs)
    for (int i = t; i < cnt; i += 1024) {
        unsigned long long r = sorted[i];
        unsigned int slab = (unsigned int)(r >> 16) & 1023u;
        unsigned int pos = gbase[slab] + ((unsigned int)i - offs[slab]);
        if (pos < (unsigned int)SLAB_SLOTS)
            out64[(long long)slab * SLAB_SLOTS + pos] = r;
    }
    // zero-fill pad slots (rec==0 is a no-op downstream)
    for (unsigned int j = h; j < hpad; ++j) {
        unsigned int pos = gbase[t] + j;
        if (pos < (unsigned int)SLAB_SLOTS)
            out64[(long long)t * SLAB_SLOTS + pos] = 0ull;
    }
}

// ------- resolve: slab list -> 8 per-row LDS lists -> key tables -> rows -------

__global__ __launch_bounds__(1024) void resolve_slab(
        unsigned int* __restrict__ out32,
        const unsigned int* __restrict__ slabcur,
        const float* __restrict__ b) {
    __shared__ unsigned long long sub[SLAB_ROWS][SUB_CAP];  // 96 KB
    __shared__ unsigned int scnt[SLAB_ROWS];
    __shared__ unsigned int tab[NROW];                      // 32 KB
    const unsigned int s = blockIdx.x;
    const int t = threadIdx.x;

    if (t < SLAB_ROWS) scnt[t] = 0u;
    __syncthreads();

    unsigned int cnt = slabcur[s * CUR_PAD];
    if (cnt > (unsigned int)SLAB_SLOTS) cnt = SLAB_SLOTS;
    const unsigned long long* list =
        (const unsigned long long*)out32 + (long long)s * SLAB_SLOTS;
    const uintx4* list4 = reinterpret_cast<const uintx4*>(list);
    unsigned int cnt2 = cnt >> 1;                  // cnt is a multiple of 8
    for (unsigned int i = t; i < cnt2; i += 1024) {
        uintx4 v = __builtin_nontemporal_load(&list4[i]);
        unsigned long long r0 = ((unsigned long long)v.y << 32) | v.x;
        unsigned long long r1 = ((unsigned long long)v.w << 32) | v.z;
        if (r0) {
            unsigned int row = ((unsigned int)(r0 >> 13)) & 7u;
            unsigned int pos = atomicAdd(&scnt[row], 1u);
            if (pos < (unsigned int)SUB_CAP) sub[row][pos] = r0;
        }
        if (r1) {
            unsigned int row = ((unsigned int)(r1 >> 13)) & 7u;
            unsigned int pos = atomicAdd(&scnt[row], 1u);
            if (pos < (unsigned int)SUB_CAP) sub[row][pos] = r1;
        }
    }
    __syncthreads();

    const float b0 = b[0], b1 = b[1], b2 = b[2], b3 = b[3], b4 = b[4];
    uint4* t4 = (uint4*)tab;

    for (int r = 0; r < SLAB_ROWS; ++r) {
        // zero key table
        #pragma unroll
        for (int j = 0; j < 2; ++j) t4[t + j * 1024] = make_uint4(0u, 0u, 0u, 0u);
        __syncthreads();

        unsigned int c = scnt[r];
        if (c > (unsigned int)SUB_CAP) c = SUB_CAP;
        for (unsigned int i = t; i < c; i += 1024) {
            unsigned long long rec = sub[r][i];
            atomicMax(&tab[(unsigned int)rec & 8191u], (unsigned int)(rec >> 26));
        }
        __syncthreads();

        // decode + write row 8s+r (nontemporal; row no longer needed as storage)
        floatx4* orow = reinterpret_cast<floatx4*>(
            out32 + ((long long)(SLAB_ROWS * s + r)) * NROW);
        #pragma unroll
        for (int j = 0; j < 2; ++j) {
            uint4 k = t4[t + j * 1024];
            floatx4 v;
            v.x = dec(k.x, b0, b1, b2, b3, b4);
            v.y = dec(k.y, b0, b1, b2, b3, b4);
            v.z = dec(k.z, b0, b1, b2, b3, b4);
            v.w = dec(k.w, b0, b1, b2, b3, b4);
            __builtin_nontemporal_store(v, &orow[j * 1024 + t]);
        }
        __syncthreads();
    }
}

// ---------------- fallback path (any N): round-1 3-pass ----------------

__global__ void zero_keys_kernel(unsigned int* __restrict__ out, long long n) {
    long long n4 = n >> 2;
    long long i = (long long)blockIdx.x * blockDim.x + threadIdx.x;
    long long stride = (long long)gridDim.x * blockDim.x;
    uint4* p = reinterpret_cast<uint4*>(out);
    for (long long j = i; j < n4; j += stride) p[j] = make_uint4(0u, 0u, 0u, 0u);
    long long base = n4 << 2;
    for (long long j = base + i; j < n; j += stride) out[j] = 0u;
}

__global__ void scatter_keys_kernel(const int* __restrict__ src,
                                    const int* __restrict__ dst,
                                    const int* __restrict__ plen,
                                    unsigned int* __restrict__ keys,
                                    int E, int N) {
    int i = blockIdx.x * blockDim.x + threadIdx.x;
    int stride = gridDim.x * blockDim.x;
    for (int e = i; e < E; e += stride) {
        int s = src[e], d = dst[e], pl = plen[e];
        int bi = pl < 1 ? 0 : (pl > MAXPD ? MAXPD - 1 : pl - 1);
        unsigned int key = (((unsigned int)e + 1u) << 3) | (unsigned int)bi;
        atomicMax(keys + (long long)s * (long long)N + d, key);
    }
}

__global__ void decode_keys_kernel(unsigned int* __restrict__ data, long long n,
                                   const float* __restrict__ b) {
    __shared__ float sb[8];
    if (threadIdx.x < 8) sb[threadIdx.x] = (threadIdx.x < MAXPD) ? b[threadIdx.x] : 0.0f;
    __syncthreads();
    long long n4 = n >> 2;
    long long i = (long long)blockIdx.x * blockDim.x + threadIdx.x;
    long long stride = (long long)gridDim.x * blockDim.x;
    uint4* p = reinterpret_cast<uint4*>(data);
    float4* f = reinterpret_cast<float4*>(data);
    for (long long j = i; j < n4; j += stride) {
        uint4 k = p[j];
        float4 v;
        v.x = k.x ? sb[k.x & 7u] : 0.0f;
        v.y = k.y ? sb[k.y & 7u] : 0.0f;
        v.z = k.z ? sb[k.z & 7u] : 0.0f;
        v.w = k.w ? sb[k.w & 7u] : 0.0f;
        f[j] = v;
    }
    long long base = n4 << 2;
    float* fo = reinterpret_cast<float*>(data);
    for (long long j = base + i; j < n; j += stride) {
        unsigned int k = data[j];
        fo[j] = k ? sb[k & 7u] : 0.0f;
    }
}

extern "C" void kernel_launch(void* const* d_in, const int* in_sizes, int n_in,
                              void* d_out, int out_size, void* d_ws, size_t ws_size,
                              hipStream_t stream) {
    const int* src  = (const int*)d_in[1];
    const int* dst  = (const int*)d_in[2];
    const int* plen = (const int*)d_in[3];
    const float* b  = (const float*)d_in[4];

    int N = in_sizes[0] / 128;          // 8192
    int E = in_sizes[1];                // 8,000,000
    long long n = (long long)out_size;  // N*N

    const size_t ws_need = (size_t)NSLAB * CUR_PAD * 4;  // 64 KB of cursors

    if (N == NROW && n == (long long)NROW * NROW && E > 0 && E <= E_MAX &&
        ws_size >= ws_need) {
        unsigned int* slabcur = (unsigned int*)d_ws;     // 1024*16 u32
        unsigned long long* out64 = (unsigned long long*)d_out;
        unsigned int* out32 = (unsigned int*)d_out;

        int nzero = NSLAB * CUR_PAD;
        zero_ws_kernel<<<(nzero + 255) / 256, 256, 0, stream>>>(slabcur, nzero);

        int nchunk = (E + CHUNK - 1) / CHUNK;
        stage1_bin<<<nchunk, 1024, 0, stream>>>(src, dst, plen, out64, slabcur, E);
        resolve_slab<<<NSLAB, 1024, 0, stream>>>(out32, slabcur, b);
    } else {
        unsigned int* keys = (unsigned int*)d_out;
        const int BLK = 256;
        int grid_zero = (int)min((n / 4 + BLK - 1) / BLK, (long long)2048);
        int grid_scat = min((E + BLK - 1) / BLK, 2048);
        zero_keys_kernel<<<grid_zero, BLK, 0, stream>>>(keys, n);
        scatter_keys_kernel<<<grid_scat, BLK, 0, stream>>>(src, dst, plen, keys, E, N);
        decode_keys_kernel<<<grid_zero, BLK, 0, stream>>>(keys, n, b);
    }
}

// Round 9
// 145.190 us; speedup vs baseline: 1.0673x; 1.0673x over previous
//
#include <hip/hip_runtime.h>

// SpatialEncoding: out[N,N]=0; out[src[e],dst[e]] = b[clip(path_len[e],1,5)-1],
// last edge wins for duplicate (src,dst). Resolution via max over
// key = ((e+1)<<3)|bias_idx  (order-independent -> deterministic).
//
// Fast path (N=8192), 3 chunk-sort stages, intermediates inside d_out:
//   rec(u64) = key[51:26] | src[25:13] | dst[12:0]; rec==0 is a no-op pad.
//   stage1: chunk-sort (8192 edges/WG, 1024 thr) into 64 slabs (128 rows).
//           Slab s's list lives in s's ODD rows (64 rows = 262144 slots; mean
//           125K -> 390 sigma headroom). Runs ~128 recs = 1KB, 64B-aligned
//           (per-chunk allocations rounded to 8, zero-padded).
//   stage2: chunk-sort each slab list (8192 recs/WG) into 64 row-pair lists
//           in the slab's EVEN rows (row 2p holds pair p's list; cap 4096,
//           mean 1953, 48 sigma). Runs ~128 recs = 1KB, exact allocation
//           (global cursor = exact count; no stale-pad reads downstream).
//   stage3: per row-pair, LDS atomicMax key table (64KB), decode, write rows
//           2p, 2p+1 (nontemporal). Unchanged from round 7.

typedef float floatx4 __attribute__((ext_vector_type(4)));
typedef unsigned int uintx4 __attribute__((ext_vector_type(4)));

constexpr int MAXPD      = 5;
constexpr int NROW       = 8192;
constexpr int SLAB_ROWS  = 128;
constexpr int NSLAB      = NROW / SLAB_ROWS;       // 64
constexpr int SLOTS_ROW  = NROW / 2;               // 4096 u64 per row
constexpr int SLAB_CAP   = 64 * SLOTS_ROW;         // 262144 recs (the 64 odd rows)
constexpr int PAIR_CAP   = SLOTS_ROW;              // 4096 recs per pair list
constexpr int CHUNK      = 8192;                   // recs per sort WG (both stages)
constexpr int CUR_PAD    = 16;                     // slab cursors 1 per 64B line
constexpr int NPAIR      = NROW / 2;               // 4096
constexpr int E_MAX      = 8388606;                // (e+1)<<3 must fit 26 bits

__device__ __forceinline__ long long slab_slot(unsigned int s, unsigned int i) {
    // record i of slab s -> odd rows 128s+1,3,...,255
    unsigned int row = s * 128u + 1u + 2u * (i >> 12);
    return (long long)row * SLOTS_ROW + (i & 4095u);
}

__device__ __forceinline__ float dec(unsigned int k, float b0, float b1,
                                     float b2, float b3, float b4) {
    if (k == 0u) return 0.0f;
    unsigned int bi = k & 7u;
    float v = b0;
    v = (bi == 1u) ? b1 : v;
    v = (bi == 2u) ? b2 : v;
    v = (bi == 3u) ? b3 : v;
    v = (bi == 4u) ? b4 : v;
    return v;
}

__global__ void zero_ws_kernel(unsigned int* __restrict__ w, int n) {
    int i = blockIdx.x * blockDim.x + threadIdx.x;
    if (i < n) w[i] = 0u;
}

// ---------------- stage 1: chunk-sort edges into 64 slab lists ----------------

__global__ __launch_bounds__(1024) void stage1_bin(
        const int* __restrict__ gsrc, const int* __restrict__ gdst,
        const int* __restrict__ gpl, unsigned long long* __restrict__ out64,
        unsigned int* __restrict__ slabcur, int E) {
    __shared__ unsigned long long sorted[CHUNK];   // 64 KB
    __shared__ unsigned int hist[NSLAB];
    __shared__ unsigned int offs[NSLAB];
    __shared__ unsigned int cur2[NSLAB];
    __shared__ unsigned int gbase[NSLAB];

    const int t = threadIdx.x;
    const int base = blockIdx.x * CHUNK;
    const int cnt = min(CHUNK, E - base);

    if (t < NSLAB) hist[t] = 0u;
    __syncthreads();

    unsigned long long rec[8];

    #pragma unroll
    for (int k = 0; k < 2; ++k) {
        int g = base + (k * 1024 + t) * 4;
        bool full = (g + 3 < E);
        int4 s4 = {0,0,0,0}, d4 = {0,0,0,0}, p4 = {1,1,1,1};
        if (full) {
            s4 = ((const int4*)gsrc)[g >> 2];
            d4 = ((const int4*)gdst)[g >> 2];
            p4 = ((const int4*)gpl)[g >> 2];
        }
        #pragma unroll
        for (int j = 0; j < 4; ++j) {
            int e = g + j;
            unsigned long long r = 0ull;
            if (full || e < E) {
                int ss, dd, pp;
                if (full) {
                    ss = (j == 0) ? s4.x : (j == 1) ? s4.y : (j == 2) ? s4.z : s4.w;
                    dd = (j == 0) ? d4.x : (j == 1) ? d4.y : (j == 2) ? d4.z : d4.w;
                    pp = (j == 0) ? p4.x : (j == 1) ? p4.y : (j == 2) ? p4.z : p4.w;
                } else {
                    ss = gsrc[e]; dd = gdst[e]; pp = gpl[e];
                }
                int bi = pp < 1 ? 0 : (pp > MAXPD ? MAXPD - 1 : pp - 1);
                unsigned int key = (((unsigned int)e + 1u) << 3) | (unsigned int)bi;
                r = ((unsigned long long)key << 26) |
                    ((unsigned long long)(unsigned int)ss << 13) |
                    (unsigned long long)(unsigned int)dd;
                atomicAdd(&hist[(unsigned int)ss >> 7], 1u);   // slab = src>>7
            }
            rec[k * 4 + j] = r;
        }
    }
    __syncthreads();

    // exclusive scan of hist[64] on wave 0
    if (t < NSLAB) {
        unsigned int h = hist[t];
        unsigned int incl = h;
        #pragma unroll
        for (int d = 1; d < 64; d <<= 1) {
            unsigned int v = __shfl_up(incl, d, 64);
            if (t >= d) incl += v;
        }
        unsigned int excl = incl - h;
        offs[t] = excl;
        cur2[t] = excl;
        unsigned int hpad = (h + 7u) & ~7u;        // 64B-aligned global allocation
        gbase[t] = atomicAdd(&slabcur[t * CUR_PAD], hpad);
    }
    __syncthreads();

    // reorder into LDS by slab
    #pragma unroll
    for (int m = 0; m < 8; ++m) {
        unsigned long long r = rec[m];
        if (r) {
            unsigned int slab = (unsigned int)(r >> 20) & 63u;  // src>>7
            unsigned int p = atomicAdd(&cur2[slab], 1u);
            sorted[p] = r;
        }
    }
    __syncthreads();

    // write out: per-slab contiguous 64B-aligned runs (~128 recs = 1KB)
    for (int i = t; i < cnt; i += 1024) {
        unsigned long long r = sorted[i];
        unsigned int slab = (unsigned int)(r >> 20) & 63u;
        unsigned int pos = gbase[slab] + ((unsigned int)i - offs[slab]);
        if (pos < (unsigned int)SLAB_CAP) out64[slab_slot(slab, pos)] = r;
    }
    // zero-fill pad slots (rec==0 is a no-op downstream)
    if (t < NSLAB) {
        unsigned int h = hist[t];
        unsigned int hpad = (h + 7u) & ~7u;
        for (unsigned int j = h; j < hpad; ++j) {
            unsigned int pos = gbase[t] + j;
            if (pos < (unsigned int)SLAB_CAP)
                out64[slab_slot((unsigned int)t, pos)] = 0ull;
        }
    }
}

// ------- stage 2: chunk-sort each slab list into 64 row-pair lists -------

__global__ __launch_bounds__(1024) void stage2_rebin(
        unsigned long long* __restrict__ out64,
        const unsigned int* __restrict__ slabcur,
        unsigned int* __restrict__ paircur) {
    __shared__ unsigned long long sorted[CHUNK];   // 64 KB
    __shared__ unsigned int hist[NSLAB];
    __shared__ unsigned int offs[NSLAB];
    __shared__ unsigned int cur2[NSLAB];
    __shared__ unsigned int gbase[NSLAB];
    __shared__ unsigned int totnz_sh;

    const unsigned int s = blockIdx.x & 63u;       // slab
    const unsigned int c = blockIdx.x >> 6;        // chunk within slab
    const int t = threadIdx.x;

    unsigned int len = slabcur[s * CUR_PAD];
    if (len > (unsigned int)SLAB_CAP) len = SLAB_CAP;
    unsigned int start = c * (unsigned int)CHUNK;
    if (start >= len) return;                      // uniform across WG
    unsigned int cc = min((unsigned int)CHUNK, len - start);  // multiple of 8

    if (t < NSLAB) hist[t] = 0u;
    __syncthreads();

    unsigned long long rec[8];
    #pragma unroll
    for (int k = 0; k < 2; ++k) {
        unsigned int bidx = ((unsigned int)(k * 1024 + t)) * 4u;
        bool has = (bidx < cc);
        #pragma unroll
        for (int j2 = 0; j2 < 2; ++j2) {
            unsigned long long r0 = 0ull, r1 = 0ull;
            if (has) {
                long long slot = slab_slot(s, start + bidx + 2u * j2);
                uintx4 v = __builtin_nontemporal_load(
                    reinterpret_cast<const uintx4*>(&out64[slot]));
                r0 = ((unsigned long long)v.y << 32) | v.x;
                r1 = ((unsigned long long)v.w << 32) | v.z;
                if (r0) atomicAdd(&hist[(unsigned int)(r0 >> 14) & 63u], 1u);
                if (r1) atomicAdd(&hist[(unsigned int)(r1 >> 14) & 63u], 1u);
            }
            rec[k * 4 + 2 * j2]     = r0;
            rec[k * 4 + 2 * j2 + 1] = r1;
        }
    }
    __syncthreads();

    // exclusive scan of hist[64] on wave 0; exact global allocation
    if (t < NSLAB) {
        unsigned int h = hist[t];
        unsigned int incl = h;
        #pragma unroll
        for (int d = 1; d < 64; d <<= 1) {
            unsigned int v = __shfl_up(incl, d, 64);
            if (t >= d) incl += v;
        }
        unsigned int excl = incl - h;
        offs[t] = excl;
        cur2[t] = excl;
        if (t == 63) totnz_sh = excl + h;
        gbase[t] = h ? atomicAdd(&paircur[s * 64u + t], h) : 0u;
    }
    __syncthreads();

    // reorder nonzero recs into LDS by pair bin
    #pragma unroll
    for (int m = 0; m < 8; ++m) {
        unsigned long long r = rec[m];
        if (r) {
            unsigned int q = (unsigned int)(r >> 14) & 63u;   // (src>>1)&63
            unsigned int p = atomicAdd(&cur2[q], 1u);
            sorted[p] = r;
        }
    }
    __syncthreads();

    // write out: per-pair contiguous runs (~128 recs = 1KB), exact counts
    unsigned int tot = totnz_sh;
    for (unsigned int i = t; i < tot; i += 1024) {
        unsigned long long r = sorted[i];
        unsigned int q = (unsigned int)(r >> 14) & 63u;
        unsigned int pos = gbase[q] + (i - offs[q]);
        if (pos < (unsigned int)PAIR_CAP) {
            unsigned int row = s * 128u + 2u * q;             // even row = 2*pair
            out64[(long long)row * SLOTS_ROW + pos] = r;
        }
    }
}

// ---------------- stage 3: resolve pair list, decode, write 2 rows ----------------

__global__ __launch_bounds__(1024) void stage3_resolve(
        unsigned int* __restrict__ out32,
        const unsigned int* __restrict__ paircur,
        const float* __restrict__ b) {
    __shared__ unsigned int tab[2 * NROW];   // 64 KB
    const int p = blockIdx.x, t = threadIdx.x;
    uint4* t4 = (uint4*)tab;
    #pragma unroll
    for (int j = 0; j < 4; ++j) t4[t + j * 1024] = make_uint4(0u, 0u, 0u, 0u);
    __syncthreads();

    unsigned int cnt = paircur[p];
    if (cnt > (unsigned int)PAIR_CAP) cnt = PAIR_CAP;
    const unsigned long long* list =
        (const unsigned long long*)out32 + (long long)(2 * p) * SLOTS_ROW;
    const uintx4* list4 = reinterpret_cast<const uintx4*>(list);
    unsigned int cnt2 = cnt >> 1;
    for (unsigned int i = t; i < cnt2; i += 1024) {
        uintx4 v = __builtin_nontemporal_load(&list4[i]);
        unsigned long long r0 = ((unsigned long long)v.y << 32) | v.x;
        unsigned long long r1 = ((unsigned long long)v.w << 32) | v.z;
        atomicMax(&tab[(((unsigned int)(r0 >> 13)) & 1u) * NROW +
                       ((unsigned int)r0 & 8191u)],
                  (unsigned int)(r0 >> 26));
        atomicMax(&tab[(((unsigned int)(r1 >> 13)) & 1u) * NROW +
                       ((unsigned int)r1 & 8191u)],
                  (unsigned int)(r1 >> 26));
    }
    if (t == 0 && (cnt & 1u)) {
        unsigned long long r = list[cnt - 1u];
        atomicMax(&tab[(((unsigned int)(r >> 13)) & 1u) * NROW +
                       ((unsigned int)r & 8191u)],
                  (unsigned int)(r >> 26));
    }
    __syncthreads();

    const float b0 = b[0], b1 = b[1], b2 = b[2], b3 = b[3], b4 = b[4];
    floatx4* orow = reinterpret_cast<floatx4*>(out32 + (long long)(2 * p) * NROW);
    #pragma unroll
    for (int j = 0; j < 4; ++j) {
        uint4 k = t4[t + j * 1024];
        floatx4 v;
        v.x = dec(k.x, b0, b1, b2, b3, b4);
        v.y = dec(k.y, b0, b1, b2, b3, b4);
        v.z = dec(k.z, b0, b1, b2, b3, b4);
        v.w = dec(k.w, b0, b1, b2, b3, b4);
        __builtin_nontemporal_store(v, &orow[j * 1024 + t]);
    }
}

// ---------------- fallback path (any N): round-1 3-pass ----------------

__global__ void zero_keys_kernel(unsigned int* __restrict__ out, long long n) {
    long long n4 = n >> 2;
    long long i = (long long)blockIdx.x * blockDim.x + threadIdx.x;
    long long stride = (long long)gridDim.x * blockDim.x;
    uint4* p = reinterpret_cast<uint4*>(out);
    for (long long j = i; j < n4; j += stride) p[j] = make_uint4(0u, 0u, 0u, 0u);
    long long base = n4 << 2;
    for (long long j = base + i; j < n; j += stride) out[j] = 0u;
}

__global__ void scatter_keys_kernel(const int* __restrict__ src,
                                    const int* __restrict__ dst,
                                    const int* __restrict__ plen,
                                    unsigned int* __restrict__ keys,
                                    int E, int N) {
    int i = blockIdx.x * blockDim.x + threadIdx.x;
    int stride = gridDim.x * blockDim.x;
    for (int e = i; e < E; e += stride) {
        int s = src[e], d = dst[e], pl = plen[e];
        int bi = pl < 1 ? 0 : (pl > MAXPD ? MAXPD - 1 : pl - 1);
        unsigned int key = (((unsigned int)e + 1u) << 3) | (unsigned int)bi;
        atomicMax(keys + (long long)s * (long long)N + d, key);
    }
}

__global__ void decode_keys_kernel(unsigned int* __restrict__ data, long long n,
                                   const float* __restrict__ b) {
    __shared__ float sb[8];
    if (threadIdx.x < 8) sb[threadIdx.x] = (threadIdx.x < MAXPD) ? b[threadIdx.x] : 0.0f;
    __syncthreads();
    long long n4 = n >> 2;
    long long i = (long long)blockIdx.x * blockDim.x + threadIdx.x;
    long long stride = (long long)gridDim.x * blockDim.x;
    uint4* p = reinterpret_cast<uint4*>(data);
    float4* f = reinterpret_cast<float4*>(data);
    for (long long j = i; j < n4; j += stride) {
        uint4 k = p[j];
        float4 v;
        v.x = k.x ? sb[k.x & 7u] : 0.0f;
        v.y = k.y ? sb[k.y & 7u] : 0.0f;
        v.z = k.z ? sb[k.z & 7u] : 0.0f;
        v.w = k.w ? sb[k.w & 7u] : 0.0f;
        f[j] = v;
    }
    long long base = n4 << 2;
    float* fo = reinterpret_cast<float*>(data);
    for (long long j = base + i; j < n; j += stride) {
        unsigned int k = data[j];
        fo[j] = k ? sb[k & 7u] : 0.0f;
    }
}

extern "C" void kernel_launch(void* const* d_in, const int* in_sizes, int n_in,
                              void* d_out, int out_size, void* d_ws, size_t ws_size,
                              hipStream_t stream) {
    const int* src  = (const int*)d_in[1];
    const int* dst  = (const int*)d_in[2];
    const int* plen = (const int*)d_in[3];
    const float* b  = (const float*)d_in[4];

    int N = in_sizes[0] / 128;          // 8192
    int E = in_sizes[1];                // 8,000,000
    long long n = (long long)out_size;  // N*N

    const int ncur = NSLAB * CUR_PAD + NPAIR;        // slabcur + paircur
    const size_t ws_need = (size_t)ncur * 4;         // ~20 KB

    if (N == NROW && n == (long long)NROW * NROW && E > 0 && E <= E_MAX &&
        ws_size >= ws_need) {
        unsigned int* slabcur = (unsigned int*)d_ws;           // 64*16 u32
        unsigned int* paircur = slabcur + NSLAB * CUR_PAD;     // 4096 u32
        unsigned long long* out64 = (unsigned long long*)d_out;
        unsigned int* out32 = (unsigned int*)d_out;

        zero_ws_kernel<<<(ncur + 255) / 256, 256, 0, stream>>>(slabcur, ncur);

        int nchunk = (E + CHUNK - 1) / CHUNK;
        stage1_bin<<<nchunk, 1024, 0, stream>>>(src, dst, plen, out64, slabcur, E);
        stage2_rebin<<<NSLAB * 32, 1024, 0, stream>>>(out64, slabcur, paircur);
        stage3_resolve<<<NPAIR, 1024, 0, stream>>>(out32, paircur, b);
    } else {
        unsigned int* keys = (unsigned int*)d_out;
        const int BLK = 256;
        int grid_zero = (int)min((n / 4 + BLK - 1) / BLK, (long long)2048);
        int grid_scat = min((E + BLK - 1) / BLK, 2048);
        zero_keys_kernel<<<grid_zero, BLK, 0, stream>>>(keys, n);
        scatter_keys_kernel<<<grid_scat, BLK, 0, stream>>>(src, dst, plen, keys, E, N);
        decode_keys_kernel<<<grid_zero, BLK, 0, stream>>>(keys, n, b);
    }
}

// Round 10
// 142.588 us; speedup vs baseline: 1.0868x; 1.0182x over previous
//
#include <hip/hip_runtime.h>

// SpatialEncoding: out[N,N]=0; out[src[e],dst[e]] = b[clip(path_len[e],1,5)-1],
// last edge wins for duplicate (src,dst). Resolution via max over
// key = ((e+1)<<3)|bias_idx  (order-independent -> deterministic).
//
// Fast path (N=8192), 2 kernels, intermediates inside d_out:
//   rec(u64) = key[51:26] | src[25:13] | dst[12:0]; rec==0 is a no-op pad.
//   stage1: chunk-sort (8192 edges/WG, 1024 thr) into 256 slabs (32 rows);
//           slab s's list lives in s's ODD rows (9 rows = 36864 slots; mean
//           31250, 32 sigma). Per-chunk allocations rounded to 8 recs (64B),
//           zero-padded -> line-aligned 256B runs.
//   fused stage2+3 (one WG per slab):
//     phase 1: bin slab list (NT reads) into 16 pair lists in the slab's EVEN
//              rows (normal stores -> stay in local XCD L2; cap 4096, exact).
//     phase 2: per pair q: zero 64KB LDS key table, atomicMax from pair list
//              (L2-hot re-read), decode, NT-write rows 32s+2q, 32s+2q+1.
//     Ordering: slab list fully consumed before any phase-2 write; pair q's
//     decode overwrites only its own consumed list. __syncthreads drains
//     vmcnt -> phase-1 stores L2-visible before phase-2 reads.

typedef float floatx4 __attribute__((ext_vector_type(4)));
typedef unsigned int uintx4 __attribute__((ext_vector_type(4)));

constexpr int MAXPD      = 5;
constexpr int NROW       = 8192;
constexpr int SLAB_ROWS  = 32;
constexpr int NSLAB      = NROW / SLAB_ROWS;   // 256
constexpr int SLOTS_ROW  = NROW / 2;           // 4096 u64 per row
constexpr int STRIDE     = 9 * SLOTS_ROW;      // 36864 records per slab list
constexpr int PAIR_CAP   = SLOTS_ROW;          // 4096 records per pair list
constexpr int CHUNK      = 8192;               // edges per stage-1 WG
constexpr int CUR_PAD    = 16;                 // slab cursors 1 per 64B line
constexpr int E_MAX      = 8388606;            // (e+1)<<3 must fit 26 bits

__device__ __forceinline__ long long slab_slot(unsigned int s, unsigned int i) {
    // record i of slab s -> odd rows 32s+1,3,...,17
    unsigned int row = s * 32u + 1u + 2u * (i >> 12);
    return (long long)row * SLOTS_ROW + (i & 4095u);
}

__device__ __forceinline__ float dec(unsigned int k, float b0, float b1,
                                     float b2, float b3, float b4) {
    if (k == 0u) return 0.0f;
    unsigned int bi = k & 7u;
    float v = b0;
    v = (bi == 1u) ? b1 : v;
    v = (bi == 2u) ? b2 : v;
    v = (bi == 3u) ? b3 : v;
    v = (bi == 4u) ? b4 : v;
    return v;
}

__global__ void zero_ws_kernel(unsigned int* __restrict__ w, int n) {
    int i = blockIdx.x * blockDim.x + threadIdx.x;
    if (i < n) w[i] = 0u;
}

// ---------------- stage 1: chunk-sort edges into slab lists ----------------

__global__ __launch_bounds__(1024) void stage1_bin(
        const int* __restrict__ gsrc, const int* __restrict__ gdst,
        const int* __restrict__ gpl, unsigned long long* __restrict__ out64,
        unsigned int* __restrict__ slabcur, int E) {
    __shared__ unsigned long long sorted[CHUNK];   // 64 KB
    __shared__ unsigned int hist[NSLAB];
    __shared__ unsigned int offs[NSLAB];
    __shared__ unsigned int cur2[NSLAB];
    __shared__ unsigned int gbase[NSLAB];
    __shared__ unsigned int wsum[4];

    const int t = threadIdx.x;
    const int base = blockIdx.x * CHUNK;
    const int cnt = min(CHUNK, E - base);

    if (t < NSLAB) hist[t] = 0u;
    __syncthreads();

    unsigned long long rec[8];

    #pragma unroll
    for (int k = 0; k < 2; ++k) {
        int g = base + (k * 1024 + t) * 4;
        bool full = (g + 3 < E);
        int4 s4 = {0,0,0,0}, d4 = {0,0,0,0}, p4 = {1,1,1,1};
        if (full) {
            s4 = ((const int4*)gsrc)[g >> 2];
            d4 = ((const int4*)gdst)[g >> 2];
            p4 = ((const int4*)gpl)[g >> 2];
        }
        #pragma unroll
        for (int j = 0; j < 4; ++j) {
            int e = g + j;
            unsigned long long r = 0ull;
            if (full || e < E) {
                int ss, dd, pp;
                if (full) {
                    ss = (j == 0) ? s4.x : (j == 1) ? s4.y : (j == 2) ? s4.z : s4.w;
                    dd = (j == 0) ? d4.x : (j == 1) ? d4.y : (j == 2) ? d4.z : d4.w;
                    pp = (j == 0) ? p4.x : (j == 1) ? p4.y : (j == 2) ? p4.z : p4.w;
                } else {
                    ss = gsrc[e]; dd = gdst[e]; pp = gpl[e];
                }
                int bi = pp < 1 ? 0 : (pp > MAXPD ? MAXPD - 1 : pp - 1);
                unsigned int key = (((unsigned int)e + 1u) << 3) | (unsigned int)bi;
                r = ((unsigned long long)key << 26) |
                    ((unsigned long long)(unsigned int)ss << 13) |
                    (unsigned long long)(unsigned int)dd;
                atomicAdd(&hist[(unsigned int)ss >> 5], 1u);
            }
            rec[k * 4 + j] = r;
        }
    }
    __syncthreads();

    // exclusive scan of hist[256] over threads 0..255 (4 full waves)
    unsigned int h = 0, incl = 0;
    if (t < NSLAB) {
        h = hist[t];
        incl = h;
        #pragma unroll
        for (int d = 1; d < 64; d <<= 1) {
            unsigned int v = __shfl_up(incl, d, 64);
            if ((t & 63) >= d) incl += v;
        }
        if ((t & 63) == 63) wsum[t >> 6] = incl;
    }
    __syncthreads();
    if (t < NSLAB) {
        unsigned int wpre = 0;
        for (int w = 0; w < (t >> 6); ++w) wpre += wsum[w];
        unsigned int excl = wpre + incl - h;
        offs[t] = excl;
        cur2[t] = excl;
        unsigned int hpad = (h + 7u) & ~7u;        // 64B-aligned allocation
        gbase[t] = atomicAdd(&slabcur[t * CUR_PAD], hpad);
    }
    __syncthreads();

    // reorder into LDS by slab
    #pragma unroll
    for (int m = 0; m < 8; ++m) {
        unsigned long long r = rec[m];
        if (r) {
            unsigned int slab = (unsigned int)(r >> 18) & 255u;  // src>>5
            unsigned int p = atomicAdd(&cur2[slab], 1u);
            sorted[p] = r;
        }
    }
    __syncthreads();

    // write out: per-slab contiguous 64B-aligned runs (~32 recs = 256B)
    for (int i = t; i < cnt; i += 1024) {
        unsigned long long r = sorted[i];
        unsigned int slab = (unsigned int)(r >> 18) & 255u;
        unsigned int pos = gbase[slab] + ((unsigned int)i - offs[slab]);
        if (pos < (unsigned int)STRIDE) out64[slab_slot(slab, pos)] = r;
    }
    // zero-fill the pad slots (rec==0 is a no-op downstream)
    if (t < NSLAB) {
        unsigned int hpad = (h + 7u) & ~7u;
        for (unsigned int j = h; j < hpad; ++j) {
            unsigned int pos = gbase[t] + j;
            if (pos < (unsigned int)STRIDE) out64[slab_slot((unsigned int)t, pos)] = 0ull;
        }
    }
}

// ------- fused stage 2+3: bin slab list -> 16 pair lists -> resolve -> rows -------

__global__ __launch_bounds__(1024) void stage2_resolve(
        unsigned int* __restrict__ out32,
        const unsigned int* __restrict__ slabcur,
        const float* __restrict__ b) {
    __shared__ unsigned int tab[2 * NROW];   // 64 KB
    __shared__ unsigned int pcur[16];
    const unsigned int s = blockIdx.x;
    const int t = threadIdx.x;
    unsigned long long* out64 = (unsigned long long*)out32;

    if (t < 16) pcur[t] = 0u;
    __syncthreads();

    // phase 1: bin slab list (NT reads) into 16 pair lists (even rows, normal stores)
    unsigned int cnt = slabcur[s * CUR_PAD];
    if (cnt > (unsigned int)STRIDE) cnt = STRIDE;
    unsigned int cnt2 = cnt >> 1;                  // cnt is a multiple of 8
    for (unsigned int i = t; i < cnt2; i += 1024) {
        long long slot = slab_slot(s, 2u * i);
        uintx4 v = __builtin_nontemporal_load(
            reinterpret_cast<const uintx4*>(&out64[slot]));
        unsigned long long r0 = ((unsigned long long)v.y << 32) | v.x;
        unsigned long long r1 = ((unsigned long long)v.w << 32) | v.z;
        if (r0) {
            unsigned int q = ((unsigned int)(r0 >> 14)) & 15u;   // (src>>1)&15
            unsigned int pos = atomicAdd(&pcur[q], 1u);
            if (pos < (unsigned int)PAIR_CAP)
                out64[(long long)(s * 32u + 2u * q) * SLOTS_ROW + pos] = r0;
        }
        if (r1) {
            unsigned int q = ((unsigned int)(r1 >> 14)) & 15u;
            unsigned int pos = atomicAdd(&pcur[q], 1u);
            if (pos < (unsigned int)PAIR_CAP)
                out64[(long long)(s * 32u + 2u * q) * SLOTS_ROW + pos] = r1;
        }
    }
    __syncthreads();   // drains vmcnt -> pair-list stores visible in L2

    const float b0 = b[0], b1 = b[1], b2 = b[2], b3 = b[3], b4 = b[4];
    uint4* t4 = (uint4*)tab;

    // phase 2: per pair, resolve + decode + write 2 rows
    for (int q = 0; q < 16; ++q) {
        #pragma unroll
        for (int j = 0; j < 4; ++j) t4[t + j * 1024] = make_uint4(0u, 0u, 0u, 0u);
        __syncthreads();

        unsigned int c = pcur[q];
        if (c > (unsigned int)PAIR_CAP) c = PAIR_CAP;
        const unsigned long long* list =
            out64 + (long long)(s * 32u + 2u * (unsigned int)q) * SLOTS_ROW;
        const uint4* list4 = reinterpret_cast<const uint4*>(list);
        unsigned int c2 = c >> 1;
        for (unsigned int i = t; i < c2; i += 1024) {
            uint4 v = list4[i];                    // normal load: L2-hot
            unsigned long long r0 = ((unsigned long long)v.y << 32) | v.x;
            unsigned long long r1 = ((unsigned long long)v.w << 32) | v.z;
            atomicMax(&tab[(((unsigned int)(r0 >> 13)) & 1u) * NROW +
                           ((unsigned int)r0 & 8191u)],
                      (unsigned int)(r0 >> 26));
            atomicMax(&tab[(((unsigned int)(r1 >> 13)) & 1u) * NROW +
                           ((unsigned int)r1 & 8191u)],
                      (unsigned int)(r1 >> 26));
        }
        if (t == 0 && (c & 1u)) {
            unsigned long long r = list[c - 1u];
            atomicMax(&tab[(((unsigned int)(r >> 13)) & 1u) * NROW +
                           ((unsigned int)r & 8191u)],
                      (unsigned int)(r >> 26));
        }
        __syncthreads();

        // decode + NT-write rows 32s+2q, 32s+2q+1 (overwrites consumed list)
        floatx4* orow = reinterpret_cast<floatx4*>(
            out32 + (long long)(s * 32u + 2u * (unsigned int)q) * NROW);
        #pragma unroll
        for (int j = 0; j < 4; ++j) {
            uint4 k = t4[t + j * 1024];
            floatx4 v;
            v.x = dec(k.x, b0, b1, b2, b3, b4);
            v.y = dec(k.y, b0, b1, b2, b3, b4);
            v.z = dec(k.z, b0, b1, b2, b3, b4);
            v.w = dec(k.w, b0, b1, b2, b3, b4);
            __builtin_nontemporal_store(v, &orow[j * 1024 + t]);
        }
        __syncthreads();
    }
}

// ---------------- fallback path (any N): round-1 3-pass ----------------

__global__ void zero_keys_kernel(unsigned int* __restrict__ out, long long n) {
    long long n4 = n >> 2;
    long long i = (long long)blockIdx.x * blockDim.x + threadIdx.x;
    long long stride = (long long)gridDim.x * blockDim.x;
    uint4* p = reinterpret_cast<uint4*>(out);
    for (long long j = i; j < n4; j += stride) p[j] = make_uint4(0u, 0u, 0u, 0u);
    long long base = n4 << 2;
    for (long long j = base + i; j < n; j += stride) out[j] = 0u;
}

__global__ void scatter_keys_kernel(const int* __restrict__ src,
                                    const int* __restrict__ dst,
                                    const int* __restrict__ plen,
                                    unsigned int* __restrict__ keys,
                                    int E, int N) {
    int i = blockIdx.x * blockDim.x + threadIdx.x;
    int stride = gridDim.x * blockDim.x;
    for (int e = i; e < E; e += stride) {
        int s = src[e], d = dst[e], pl = plen[e];
        int bi = pl < 1 ? 0 : (pl > MAXPD ? MAXPD - 1 : pl - 1);
        unsigned int key = (((unsigned int)e + 1u) << 3) | (unsigned int)bi;
        atomicMax(keys + (long long)s * (long long)N + d, key);
    }
}

__global__ void decode_keys_kernel(unsigned int* __restrict__ data, long long n,
                                   const float* __restrict__ b) {
    __shared__ float sb[8];
    if (threadIdx.x < 8) sb[threadIdx.x] = (threadIdx.x < MAXPD) ? b[threadIdx.x] : 0.0f;
    __syncthreads();
    long long n4 = n >> 2;
    long long i = (long long)blockIdx.x * blockDim.x + threadIdx.x;
    long long stride = (long long)gridDim.x * blockDim.x;
    uint4* p = reinterpret_cast<uint4*>(data);
    float4* f = reinterpret_cast<float4*>(data);
    for (long long j = i; j < n4; j += stride) {
        uint4 k = p[j];
        float4 v;
        v.x = k.x ? sb[k.x & 7u] : 0.0f;
        v.y = k.y ? sb[k.y & 7u] : 0.0f;
        v.z = k.z ? sb[k.z & 7u] : 0.0f;
        v.w = k.w ? sb[k.w & 7u] : 0.0f;
        f[j] = v;
    }
    long long base = n4 << 2;
    float* fo = reinterpret_cast<float*>(data);
    for (long long j = base + i; j < n; j += stride) {
        unsigned int k = data[j];
        fo[j] = k ? sb[k & 7u] : 0.0f;
    }
}

extern "C" void kernel_launch(void* const* d_in, const int* in_sizes, int n_in,
                              void* d_out, int out_size, void* d_ws, size_t ws_size,
                              hipStream_t stream) {
    const int* src  = (const int*)d_in[1];
    const int* dst  = (const int*)d_in[2];
    const int* plen = (const int*)d_in[3];
    const float* b  = (const float*)d_in[4];

    int N = in_sizes[0] / 128;          // 8192
    int E = in_sizes[1];                // 8,000,000
    long long n = (long long)out_size;  // N*N

    const int ncur = NSLAB * CUR_PAD;
    const size_t ws_need = (size_t)ncur * 4;  // 16 KB

    if (N == NROW && n == (long long)NROW * NROW && E > 0 && E <= E_MAX &&
        ws_size >= ws_need) {
        unsigned int* slabcur = (unsigned int*)d_ws;     // 256*16 u32
        unsigned long long* out64 = (unsigned long long*)d_out;
        unsigned int* out32 = (unsigned int*)d_out;

        zero_ws_kernel<<<(ncur + 255) / 256, 256, 0, stream>>>(slabcur, ncur);

        int nchunk = (E + CHUNK - 1) / CHUNK;
        stage1_bin<<<nchunk, 1024, 0, stream>>>(src, dst, plen, out64, slabcur, E);
        stage2_resolve<<<NSLAB, 1024, 0, stream>>>(out32, slabcur, b);
    } else {
        unsigned int* keys = (unsigned int*)d_out;
        const int BLK = 256;
        int grid_zero = (int)min((n / 4 + BLK - 1) / BLK, (long long)2048);
        int grid_scat = min((E + BLK - 1) / BLK, 2048);
        zero_keys_kernel<<<grid_zero, BLK, 0, stream>>>(keys, n);
        scatter_keys_kernel<<<grid_scat, BLK, 0, stream>>>(src, dst, plen, keys, E, N);
        decode_keys_kernel<<<grid_zero, BLK, 0, stream>>>(keys, n, b);
    }
}

// Round 11
// 137.538 us; speedup vs baseline: 1.1267x; 1.0367x over previous
//
#include <hip/hip_runtime.h>

// SpatialEncoding: out[N,N]=0; out[src[e],dst[e]] = b[clip(path_len[e],1,5)-1],
// last edge wins for duplicate (src,dst). Resolution via max over
// key = ((e+1)<<3)|bias_idx  (order-independent -> deterministic).
//
// Round-7 configuration (measured best: 138.0 µs; r8/r9/r10 variants all
// regressed or were neutral). 3-stage hierarchical binning, intermediates
// inside d_out:
//   rec(u64) = key[51:26] | src[25:13] | dst[12:0]; rec==0 is a no-op pad.
//   stage1: chunk-sort (8192 edges/WG, 1024 thr) into 256 slabs (32 rows);
//           slab s's list lives in s's ODD rows (9 rows = 36864 slots; mean
//           31250, 32 sigma). Per-chunk allocations rounded to 8 recs (64B),
//           zero-padded -> line-aligned 256B runs, no partial-line RMW.
//   stage2: per slab, re-bin list into 16 row-pair lists in s's EVEN rows
//           (cap 4096/pair, 20+ sigma). Odd/even disjoint -> no race.
//   stage3: per row-pair, LDS atomicMax key table (64KB), decode, write 2
//           rows (nontemporal loads + stores).

typedef float floatx4 __attribute__((ext_vector_type(4)));
typedef unsigned int uintx4 __attribute__((ext_vector_type(4)));

constexpr int MAXPD      = 5;
constexpr int NROW       = 8192;
constexpr int SLAB_ROWS  = 32;
constexpr int NSLAB      = NROW / SLAB_ROWS;   // 256
constexpr int SLOTS_ROW  = NROW / 2;           // 4096 u64 per row
constexpr int STRIDE     = 9 * SLOTS_ROW;      // 36864 records per slab list
constexpr int PAIR_CAP   = SLOTS_ROW;          // 4096 records per pair list
constexpr int CHUNK      = 8192;               // edges per stage-1 WG
constexpr int CUR_PAD    = 16;                 // slab cursors 1 per 64B line
constexpr int E_MAX      = 8388606;            // (e+1)<<3 must fit 26 bits

__device__ __forceinline__ long long slab_slot(unsigned int s, unsigned int i) {
    // record i of slab s -> odd rows 32s+1,3,...,17
    unsigned int row = s * 32u + 1u + 2u * (i >> 12);
    return (long long)row * SLOTS_ROW + (i & 4095u);
}

__device__ __forceinline__ float dec(unsigned int k, float b0, float b1,
                                     float b2, float b3, float b4) {
    if (k == 0u) return 0.0f;
    unsigned int bi = k & 7u;
    float v = b0;
    v = (bi == 1u) ? b1 : v;
    v = (bi == 2u) ? b2 : v;
    v = (bi == 3u) ? b3 : v;
    v = (bi == 4u) ? b4 : v;
    return v;
}

__global__ void zero_ws_kernel(unsigned int* __restrict__ w, int n) {
    int i = blockIdx.x * blockDim.x + threadIdx.x;
    if (i < n) w[i] = 0u;
}

// ---------------- stage 1: chunk-sort edges into slab lists ----------------

__global__ __launch_bounds__(1024) void stage1_bin(
        const int* __restrict__ gsrc, const int* __restrict__ gdst,
        const int* __restrict__ gpl, unsigned long long* __restrict__ out64,
        unsigned int* __restrict__ slabcur, int E) {
    __shared__ unsigned long long sorted[CHUNK];   // 64 KB
    __shared__ unsigned int hist[NSLAB];
    __shared__ unsigned int offs[NSLAB];
    __shared__ unsigned int cur2[NSLAB];
    __shared__ unsigned int gbase[NSLAB];
    __shared__ unsigned int wsum[4];

    const int t = threadIdx.x;
    const int base = blockIdx.x * CHUNK;
    const int cnt = min(CHUNK, E - base);

    if (t < NSLAB) hist[t] = 0u;
    __syncthreads();

    unsigned long long rec[8];

    #pragma unroll
    for (int k = 0; k < 2; ++k) {
        int g = base + (k * 1024 + t) * 4;
        bool full = (g + 3 < E);
        int4 s4 = {0,0,0,0}, d4 = {0,0,0,0}, p4 = {1,1,1,1};
        if (full) {
            s4 = ((const int4*)gsrc)[g >> 2];
            d4 = ((const int4*)gdst)[g >> 2];
            p4 = ((const int4*)gpl)[g >> 2];
        }
        #pragma unroll
        for (int j = 0; j < 4; ++j) {
            int e = g + j;
            unsigned long long r = 0ull;
            if (full || e < E) {
                int ss, dd, pp;
                if (full) {
                    ss = (j == 0) ? s4.x : (j == 1) ? s4.y : (j == 2) ? s4.z : s4.w;
                    dd = (j == 0) ? d4.x : (j == 1) ? d4.y : (j == 2) ? d4.z : d4.w;
                    pp = (j == 0) ? p4.x : (j == 1) ? p4.y : (j == 2) ? p4.z : p4.w;
                } else {
                    ss = gsrc[e]; dd = gdst[e]; pp = gpl[e];
                }
                int bi = pp < 1 ? 0 : (pp > MAXPD ? MAXPD - 1 : pp - 1);
                unsigned int key = (((unsigned int)e + 1u) << 3) | (unsigned int)bi;
                r = ((unsigned long long)key << 26) |
                    ((unsigned long long)(unsigned int)ss << 13) |
                    (unsigned long long)(unsigned int)dd;
                atomicAdd(&hist[(unsigned int)ss >> 5], 1u);
            }
            rec[k * 4 + j] = r;
        }
    }
    __syncthreads();

    // exclusive scan of hist[256] over threads 0..255 (4 full waves)
    unsigned int h = 0, incl = 0;
    if (t < NSLAB) {
        h = hist[t];
        incl = h;
        #pragma unroll
        for (int d = 1; d < 64; d <<= 1) {
            unsigned int v = __shfl_up(incl, d, 64);
            if ((t & 63) >= d) incl += v;
        }
        if ((t & 63) == 63) wsum[t >> 6] = incl;
    }
    __syncthreads();
    if (t < NSLAB) {
        unsigned int wpre = 0;
        for (int w = 0; w < (t >> 6); ++w) wpre += wsum[w];
        unsigned int excl = wpre + incl - h;
        offs[t] = excl;
        cur2[t] = excl;
        // allocate rounded up to 8 recs (64B) for line-aligned runs
        unsigned int hpad = (h + 7u) & ~7u;
        gbase[t] = atomicAdd(&slabcur[t * CUR_PAD], hpad);
    }
    __syncthreads();

    // reorder into LDS by slab
    #pragma unroll
    for (int m = 0; m < 8; ++m) {
        unsigned long long r = rec[m];
        if (r) {
            unsigned int slab = (unsigned int)(r >> 18) & 255u;  // src>>5
            unsigned int p = atomicAdd(&cur2[slab], 1u);
            sorted[p] = r;
        }
    }
    __syncthreads();

    // write out: per-slab contiguous 64B-aligned runs (~32 recs = 256B)
    for (int i = t; i < cnt; i += 1024) {
        unsigned long long r = sorted[i];
        unsigned int slab = (unsigned int)(r >> 18) & 255u;
        unsigned int pos = gbase[slab] + ((unsigned int)i - offs[slab]);
        if (pos < (unsigned int)STRIDE) out64[slab_slot(slab, pos)] = r;
    }
    // zero-fill the pad slots (rec==0 is a no-op downstream)
    if (t < NSLAB) {
        unsigned int hpad = (h + 7u) & ~7u;
        for (unsigned int j = h; j < hpad; ++j) {
            unsigned int pos = gbase[t] + j;
            if (pos < (unsigned int)STRIDE) out64[slab_slot((unsigned int)t, pos)] = 0ull;
        }
    }
}

// ---------------- stage 2: slab list -> 16 row-pair lists ----------------

__device__ __forceinline__ void s2_process(unsigned long long r,
                                           unsigned int* pcur,
                                           unsigned long long* out64,
                                           unsigned int s) {
    if (!r) return;                                          // pad record
    unsigned int q = ((unsigned int)(r >> 14)) & 15u;        // (src>>1)&15
    unsigned int pos = atomicAdd(&pcur[q], 1u);
    if (pos < (unsigned int)PAIR_CAP) {
        unsigned int row = s * 32u + 2u * q;                 // even row (write)
        out64[(long long)row * SLOTS_ROW + pos] = r;
    }
}

__global__ __launch_bounds__(1024) void stage2_rebin(
        unsigned long long* __restrict__ out64,
        const unsigned int* __restrict__ slabcur,
        unsigned int* __restrict__ paircnt) {
    __shared__ unsigned int pcur[16];
    const unsigned int s = blockIdx.x;
    const int t = threadIdx.x;
    if (t < 16) pcur[t] = 0u;
    __syncthreads();
    unsigned int cnt = slabcur[s * CUR_PAD];
    if (cnt > (unsigned int)STRIDE) cnt = STRIDE;
    unsigned int cnt2 = cnt >> 1;                             // cnt is multiple of 8
    for (unsigned int i = t; i < cnt2; i += 1024) {
        long long slot = slab_slot(s, 2u * i);
        uint4 v = *reinterpret_cast<const uint4*>(&out64[slot]);
        unsigned long long r0 = ((unsigned long long)v.y << 32) | v.x;
        unsigned long long r1 = ((unsigned long long)v.w << 32) | v.z;
        s2_process(r0, pcur, out64, s);
        s2_process(r1, pcur, out64, s);
    }
    if (t == 0 && (cnt & 1u)) {
        s2_process(out64[slab_slot(s, cnt - 1u)], pcur, out64, s);
    }
    __syncthreads();
    if (t < 16) {
        unsigned int c = pcur[t];
        paircnt[s * 16u + t] = (c > (unsigned int)PAIR_CAP) ? (unsigned int)PAIR_CAP : c;
    }
}

// ---------------- stage 3: resolve pair list, decode, write 2 rows ----------------

__global__ __launch_bounds__(1024) void stage3_resolve(
        unsigned int* __restrict__ out32,
        const unsigned int* __restrict__ paircnt,
        const float* __restrict__ b) {
    __shared__ unsigned int tab[2 * NROW];   // 64 KB
    const int p = blockIdx.x, t = threadIdx.x;
    uint4* t4 = (uint4*)tab;
    #pragma unroll
    for (int j = 0; j < 4; ++j) t4[t + j * 1024] = make_uint4(0u, 0u, 0u, 0u);
    __syncthreads();

    unsigned int cnt = paircnt[p];
    const unsigned long long* list =
        (const unsigned long long*)out32 + (long long)(2 * p) * SLOTS_ROW;
    const uintx4* list4 = reinterpret_cast<const uintx4*>(list);
    unsigned int cnt2 = cnt >> 1;
    for (unsigned int i = t; i < cnt2; i += 1024) {
        uintx4 v = __builtin_nontemporal_load(&list4[i]);
        unsigned long long r0 = ((unsigned long long)v.y << 32) | v.x;
        unsigned long long r1 = ((unsigned long long)v.w << 32) | v.z;
        atomicMax(&tab[(((unsigned int)(r0 >> 13)) & 1u) * NROW +
                       ((unsigned int)r0 & 8191u)],
                  (unsigned int)(r0 >> 26));
        atomicMax(&tab[(((unsigned int)(r1 >> 13)) & 1u) * NROW +
                       ((unsigned int)r1 & 8191u)],
                  (unsigned int)(r1 >> 26));
    }
    if (t == 0 && (cnt & 1u)) {
        unsigned long long r = list[cnt - 1u];
        atomicMax(&tab[(((unsigned int)(r >> 13)) & 1u) * NROW +
                       ((unsigned int)r & 8191u)],
                  (unsigned int)(r >> 26));
    }
    __syncthreads();

    const float b0 = b[0], b1 = b[1], b2 = b[2], b3 = b[3], b4 = b[4];
    floatx4* orow = reinterpret_cast<floatx4*>(out32 + (long long)(2 * p) * NROW);
    #pragma unroll
    for (int j = 0; j < 4; ++j) {
        uint4 k = t4[t + j * 1024];
        floatx4 v;
        v.x = dec(k.x, b0, b1, b2, b3, b4);
        v.y = dec(k.y, b0, b1, b2, b3, b4);
        v.z = dec(k.z, b0, b1, b2, b3, b4);
        v.w = dec(k.w, b0, b1, b2, b3, b4);
        __builtin_nontemporal_store(v, &orow[j * 1024 + t]);
    }
}

// ---------------- fallback path (any N): round-1 3-pass ----------------

__global__ void zero_keys_kernel(unsigned int* __restrict__ out, long long n) {
    long long n4 = n >> 2;
    long long i = (long long)blockIdx.x * blockDim.x + threadIdx.x;
    long long stride = (long long)gridDim.x * blockDim.x;
    uint4* p = reinterpret_cast<uint4*>(out);
    for (long long j = i; j < n4; j += stride) p[j] = make_uint4(0u, 0u, 0u, 0u);
    long long base = n4 << 2;
    for (long long j = base + i; j < n; j += stride) out[j] = 0u;
}

__global__ void scatter_keys_kernel(const int* __restrict__ src,
                                    const int* __restrict__ dst,
                                    const int* __restrict__ plen,
                                    unsigned int* __restrict__ keys,
                                    int E, int N) {
    int i = blockIdx.x * blockDim.x + threadIdx.x;
    int stride = gridDim.x * blockDim.x;
    for (int e = i; e < E; e += stride) {
        int s = src[e], d = dst[e], pl = plen[e];
        int bi = pl < 1 ? 0 : (pl > MAXPD ? MAXPD - 1 : pl - 1);
        unsigned int key = (((unsigned int)e + 1u) << 3) | (unsigned int)bi;
        atomicMax(keys + (long long)s * (long long)N + d, key);
    }
}

__global__ void decode_keys_kernel(unsigned int* __restrict__ data, long long n,
                                   const float* __restrict__ b) {
    __shared__ float sb[8];
    if (threadIdx.x < 8) sb[threadIdx.x] = (threadIdx.x < MAXPD) ? b[threadIdx.x] : 0.0f;
    __syncthreads();
    long long n4 = n >> 2;
    long long i = (long long)blockIdx.x * blockDim.x + threadIdx.x;
    long long stride = (long long)gridDim.x * blockDim.x;
    uint4* p = reinterpret_cast<uint4*>(data);
    float4* f = reinterpret_cast<float4*>(data);
    for (long long j = i; j < n4; j += stride) {
        uint4 k = p[j];
        float4 v;
        v.x = k.x ? sb[k.x & 7u] : 0.0f;
        v.y = k.y ? sb[k.y & 7u] : 0.0f;
        v.z = k.z ? sb[k.z & 7u] : 0.0f;
        v.w = k.w ? sb[k.w & 7u] : 0.0f;
        f[j] = v;
    }
    long long base = n4 << 2;
    float* fo = reinterpret_cast<float*>(data);
    for (long long j = base + i; j < n; j += stride) {
        unsigned int k = data[j];
        fo[j] = k ? sb[k & 7u] : 0.0f;
    }
}

extern "C" void kernel_launch(void* const* d_in, const int* in_sizes, int n_in,
                              void* d_out, int out_size, void* d_ws, size_t ws_size,
                              hipStream_t stream) {
    const int* src  = (const int*)d_in[1];
    const int* dst  = (const int*)d_in[2];
    const int* plen = (const int*)d_in[3];
    const float* b  = (const float*)d_in[4];

    int N = in_sizes[0] / 128;          // 8192
    int E = in_sizes[1];                // 8,000,000
    long long n = (long long)out_size;  // N*N

    const size_t ws_need = (size_t)(NSLAB * CUR_PAD + NSLAB * 16) * 4;  // 32 KB

    if (N == NROW && n == (long long)NROW * NROW && E > 0 && E <= E_MAX &&
        ws_size >= ws_need) {
        unsigned int* slabcur = (unsigned int*)d_ws;               // 256*16 u32
        unsigned int* paircnt = slabcur + NSLAB * CUR_PAD;         // 4096 u32
        unsigned long long* out64 = (unsigned long long*)d_out;
        unsigned int* out32 = (unsigned int*)d_out;

        int nzero = NSLAB * CUR_PAD;
        zero_ws_kernel<<<(nzero + 255) / 256, 256, 0, stream>>>(slabcur, nzero);

        int nchunk = (E + CHUNK - 1) / CHUNK;
        stage1_bin<<<nchunk, 1024, 0, stream>>>(src, dst, plen, out64, slabcur, E);
        stage2_rebin<<<NSLAB, 1024, 0, stream>>>(out64, slabcur, paircnt);
        stage3_resolve<<<NROW / 2, 1024, 0, stream>>>(out32, paircnt, b);
    } else {
        unsigned int* keys = (unsigned int*)d_out;
        const int BLK = 256;
        int grid_zero = (int)min((n / 4 + BLK - 1) / BLK, (long long)2048);
        int grid_scat = min((E + BLK - 1) / BLK, 2048);
        zero_keys_kernel<<<grid_zero, BLK, 0, stream>>>(keys, n);
        scatter_keys_kernel<<<grid_scat, BLK, 0, stream>>>(src, dst, plen, keys, E, N);
        decode_keys_kernel<<<grid_zero, BLK, 0, stream>>>(keys, n, b);
    }
}